// Round 4
// baseline (879.130 us; speedup 1.0000x reference)
//
#include <hip/hip_runtime.h>

#define BB 4
#define NN 1024
#define KK 100
#define TT 2
#define HH 64
#define FF 96
#define KPW 25   // k's per wave (KK / 4 waves)

// d_out layout (floats): Etot [0,4) | Ei [4,4100) | Force [4100,16388) | Virial [16388,16424)
#define OFF_EI   4
#define OFF_F    (4 + BB*NN)
#define OFF_VIR  (OFF_F + BB*NN*3)
#define OUT_TOT  (OFF_VIR + BB*9)

// d_ws layout (floats): W1T [T][H][F] at 0 | W2T [T][H][H] at TT*HH*FF
#define WS_W1T   0
#define WS_W2T   (TT*HH*FF)
#define PREP_MAX ((OUT_TOT > TT*FF*HH) ? OUT_TOT : TT*FF*HH)

__device__ __forceinline__ float wave_sum(float v) {
    #pragma unroll
    for (int off = 32; off > 0; off >>= 1)
        v += __shfl_xor(v, off, 64);
    return v;
}

// Zero d_out accumulators AND build transposed weights in one launch.
__global__ __launch_bounds__(256) void prep_kernel(
    const float* __restrict__ W1, const float* __restrict__ W2,
    float* __restrict__ ws, float* __restrict__ out)
{
    int i = blockIdx.x * 256 + threadIdx.x;
    if (i < OUT_TOT) out[i] = 0.f;
    float* W1T = ws + WS_W1T;   // [T][H][F]
    float* W2T = ws + WS_W2T;   // [T][H][H]  (W2T[t][g][h] = W2[t][h][g])
    if (i < TT * FF * HH) {
        int t = i / (FF * HH), r = i % (FF * HH);
        int f = r / HH, h = r % HH;
        W1T[(t * HH + h) * FF + f] = W1[i];
    }
    if (i < TT * HH * HH) {
        int t = i / (HH * HH), r = i % (HH * HH);
        int h = r / HH, g = r % HH;
        W2T[(t * HH + g) * HH + h] = W2[i];
    }
}

// One block (4 waves) per (b,n) row. No __syncthreads: every wave computes the
// MLP fwd+VJP redundantly in registers (all reads coalesced), then contracts
// its own contiguous 25-k chunk of dfeat.
__global__ __launch_bounds__(256) void fused_kernel(
    const float* __restrict__ feat, const int* __restrict__ tmap,
    const float* __restrict__ W1, const float* __restrict__ b1,
    const float* __restrict__ W2, const float* __restrict__ b2,
    const float* __restrict__ rdt, const float* __restrict__ Wout,
    const float* __restrict__ bout, const float* __restrict__ ws,
    const float* __restrict__ dfeat, const float* __restrict__ ImageDR,
    const int* __restrict__ neigh, float* __restrict__ out)
{
    const int row  = blockIdx.x;            // b*NN + n
    const int b    = row / NN;
    const int n    = row - b * NN;
    const int tid  = threadIdx.x;
    const int wave = tid >> 6;
    const int lane = tid & 63;
    const int k0   = wave * KPW;

    __shared__ float sdr[KK * 4];
    __shared__ int   snb[KK];

    // per-wave private preloads (no cross-wave sharing -> no barrier needed)
    {
        const float* drbase = ImageDR + (size_t)row * (KK * 4);
        for (int i = lane; i < KPW * 4; i += 64)
            sdr[k0 * 4 + i] = drbase[k0 * 4 + i];
        if (lane < KPW)
            snb[k0 + lane] = neigh[(size_t)row * KK + k0 + lane];
    }

    // ---- MLP forward + VJP, fully in registers (redundant per wave) ----
    const int t = tmap[n];
    const float* frow = feat + (size_t)row * FF;
    const float* W1t  = W1 + (size_t)t * FF * HH;
    const float* W2t  = W2 + (size_t)t * HH * HH;
    const float* W1Tt = ws + WS_W1T + (size_t)t * HH * FF;
    const float* W2Tt = ws + WS_W2T + (size_t)t * HH * HH;

    float f0 = frow[lane];
    float f1 = (lane < 32) ? frow[HH + lane] : 0.f;

    float z1 = b1[t * HH + lane];
    #pragma unroll 8
    for (int f = 0; f < HH; ++f)
        z1 = fmaf(__shfl(f0, f, 64), W1t[f * HH + lane], z1);
    #pragma unroll 8
    for (int f = 0; f < FF - HH; ++f)
        z1 = fmaf(__shfl(f1, f, 64), W1t[(HH + f) * HH + lane], z1);
    float h1 = tanhf(z1);

    float z2 = b2[t * HH + lane];
    #pragma unroll 8
    for (int h = 0; h < HH; ++h)
        z2 = fmaf(__shfl(h1, h, 64), W2t[h * HH + lane], z2);
    float u  = tanhf(z2);
    float r  = rdt[t * HH + lane];
    float wo = Wout[t * HH + lane];

    float e = wave_sum((h1 + r * u) * wo);

    float dz2 = r * wo * (1.f - u * u);
    float dh1 = wo;
    #pragma unroll 8
    for (int g = 0; g < HH; ++g)
        dh1 = fmaf(__shfl(dz2, g, 64), W2Tt[g * HH + lane], dh1);
    float dz1 = dh1 * (1.f - h1 * h1);

    float w0 = 0.f, w1 = 0.f;   // dE[lane], dE[64+lane]
    #pragma unroll 8
    for (int h = 0; h < HH; ++h) {
        const float d = __shfl(dz1, h, 64);
        w0 = fmaf(d, W1Tt[h * FF + lane], w0);
        if (lane < 32) w1 = fmaf(d, W1Tt[h * FF + HH + lane], w1);
    }

    if (wave == 0 && lane == 0) {
        const float Ei = e + bout[t];
        out[OFF_EI + row] = Ei;
        atomicAdd(&out[b], Ei);
    }

    // ---- pair contraction over this wave's contiguous k-chunk ----
    float sacc0 = 0.f, sacc1 = 0.f, sacc2 = 0.f;   // -sum_k pair_f
    float vacc  = 0.f;                             // virial entry (lanes 0..8)
    const int vx = lane / 3, vy = lane - 3 * vx;

    const size_t pbase = (size_t)row * KK;

    #pragma unroll 2
    for (int k = k0; k < k0 + KPW; ++k) {
        const float* dfp = dfeat + (pbase + k) * (FF * 3);
        float a0 = dfp[lane * 3 + 0] * w0;
        float a1 = dfp[lane * 3 + 1] * w0;
        float a2 = dfp[lane * 3 + 2] * w0;
        if (lane < 32) {
            const int m = (HH + lane) * 3;
            a0 = fmaf(dfp[m + 0], w1, a0);
            a1 = fmaf(dfp[m + 1], w1, a1);
            a2 = fmaf(dfp[m + 2], w1, a2);
        }
        float pf0 = wave_sum(a0);
        float pf1 = wave_sum(a1);
        float pf2 = wave_sum(a2);

        const int j = snb[k];
        if (j <= 0) { pf0 = 0.f; pf1 = 0.f; pf2 = 0.f; }
        else if (lane < 3) {
            const float v = (lane == 0) ? pf0 : ((lane == 1) ? pf1 : pf2);
            atomicAdd(&out[OFF_F + ((size_t)b * NN + (j - 1)) * 3 + lane], v);
        }

        sacc0 -= pf0; sacc1 -= pf1; sacc2 -= pf2;

        if (lane < 9) {
            const float rx  = sdr[k * 4 + 1 + vx];
            const float pfy = (vy == 0) ? pf0 : ((vy == 1) ? pf1 : pf2);
            vacc = fmaf(-rx, pfy, vacc);
        }
    }

    // per-wave final atomics (waves are independent)
    if (lane < 3) {
        const float s = (lane == 0) ? sacc0 : ((lane == 1) ? sacc1 : sacc2);
        atomicAdd(&out[OFF_F + (size_t)row * 3 + lane], s);
    }
    if (lane < 9) atomicAdd(&out[OFF_VIR + b * 9 + lane], vacc);
}

extern "C" void kernel_launch(void* const* d_in, const int* in_sizes, int n_in,
                              void* d_out, int out_size, void* d_ws, size_t ws_size,
                              hipStream_t stream) {
    const float* feat    = (const float*)d_in[0];
    const float* dfeat   = (const float*)d_in[1];
    const float* ImageDR = (const float*)d_in[2];
    const int*   neigh   = (const int*)  d_in[3];
    const int*   tmap    = (const int*)  d_in[4];
    const float* W1      = (const float*)d_in[5];
    const float* b1      = (const float*)d_in[6];
    const float* W2      = (const float*)d_in[7];
    const float* b2      = (const float*)d_in[8];
    const float* rdt     = (const float*)d_in[9];
    const float* Wout    = (const float*)d_in[10];
    const float* bout    = (const float*)d_in[11];

    float* out = (float*)d_out;
    float* ws  = (float*)d_ws;

    prep_kernel<<<(PREP_MAX + 255) / 256, 256, 0, stream>>>(W1, W2, ws, out);
    fused_kernel<<<BB * NN, 256, 0, stream>>>(feat, tmap, W1, b1, W2, b2, rdt,
                                              Wout, bout, ws, dfeat, ImageDR,
                                              neigh, out);
}